// Round 5
// baseline (97.547 us; speedup 1.0000x reference)
//
#include <hip/hip_runtime.h>
#include <math.h>

// Problem constants (fixed by setup_inputs)
#define BB 4
#define NI 64
#define CC 64
#define HH 256
#define WW 256
#define HW (HH * WW)

// numpy/jax "reflect" (mirror, edge not repeated), pad=1 so i in [-1, n]
__device__ __forceinline__ int refl(int i, int n) {
    i = (i < 0) ? -i : i;
    return (i >= n) ? (2 * n - 2 - i) : i;
}

// 512 threads/block = 2 channel-halves x 256 slots; each slot = 2 vertically
// adjacent pixels (64w x 4 thread-rows x 2h = 64x8 tile).
// R2 lesson: no reg cap. R3 lesson: scalarize the half index (readfirstlane).
// R4 lesson: latency-bound -> register prefetch across ni + 2 rows/thread
// (12 loads feed 162 FMAs instead of 9 feeding 81).
__global__ __launch_bounds__(512) void pff_fused2c(
    const float* __restrict__ features,
    const float* __restrict__ inpt,
    const float* __restrict__ wgt,
    const float* __restrict__ bias,
    float* __restrict__ out)
{
    __shared__ float part[2][9][256];    // 18 KB, stride-1 in slot: conflict-free

    const int tid  = threadIdx.x;
    const int half = __builtin_amdgcn_readfirstlane(tid >> 8);  // 0 or 1
    const int p    = tid & 255;
    const int wx  = blockIdx.x * 64 + (p & 63);
    const int tr  = p >> 6;                       // thread-row 0..3
    const int hy0 = blockIdx.y * 8 + tr * 2;      // even; pixel rows hy0, hy0+1
    const int b   = blockIdx.z;

    // 4 stencil rows: hy0-1 .. hy0+2 (reflect at image edges)
    const int ra = refl(hy0 - 1, HH) * WW;
    const int rb = hy0 * WW;
    const int rc = (hy0 + 1) * WW;
    const int rd = refl(hy0 + 2, HH) * WW;
    const int iw0 = refl(wx - 1, WW), iw1 = wx, iw2 = refl(wx + 1, WW);

    int off[12];
    off[0] = ra + iw0; off[1]  = ra + iw1; off[2]  = ra + iw2;
    off[3] = rb + iw0; off[4]  = rb + iw1; off[5]  = rb + iw2;
    off[6] = rc + iw0; off[7]  = rc + iw1; off[8]  = rc + iw2;
    off[9] = rd + iw0; off[10] = rd + iw1; off[11] = rd + iw2;

    float accA[9], accB[9];
    #pragma unroll
    for (int k = 0; k < 9; ++k) { accA[k] = 0.f; accB[k] = 0.f; }

    // ---- Phase 1: conv partials over this half's 32 channels ----
    const float* fb = features + (size_t)b * NI * HW + (size_t)half * 32 * HW;
    float f[12], g[12];
    #pragma unroll
    for (int t = 0; t < 12; ++t) f[t] = fb[off[t]];          // prefetch ni=0

    for (int ni = 0; ni < 32; ++ni) {
        // prefetch next channel's stencil while FMAing the current one
        if (ni < 31) {
            const float* fn = fb + (size_t)(ni + 1) * HW;
            #pragma unroll
            for (int t = 0; t < 12; ++t) g[t] = fn[off[t]];
        }
        const float* wn = wgt + (half * 32 + ni) * 9;        // scalar base
        #pragma unroll
        for (int k = 0; k < 9; ++k) {
            const float* wk = wn + k * (NI * 9);             // wgt[9][NI][3][3]
            const float w0 = wk[0], w1 = wk[1], w2 = wk[2];
            const float w3 = wk[3], w4 = wk[4], w5 = wk[5];
            const float w6 = wk[6], w7 = wk[7], w8 = wk[8];
            // pixel A: rows ra,rb,rc ; pixel B: rows rb,rc,rd
            accA[k] = fmaf(f[0], w0, accA[k]);
            accB[k] = fmaf(f[3], w0, accB[k]);
            accA[k] = fmaf(f[1], w1, accA[k]);
            accB[k] = fmaf(f[4], w1, accB[k]);
            accA[k] = fmaf(f[2], w2, accA[k]);
            accB[k] = fmaf(f[5], w2, accB[k]);
            accA[k] = fmaf(f[3], w3, accA[k]);
            accB[k] = fmaf(f[6], w3, accB[k]);
            accA[k] = fmaf(f[4], w4, accA[k]);
            accB[k] = fmaf(f[7], w4, accB[k]);
            accA[k] = fmaf(f[5], w5, accA[k]);
            accB[k] = fmaf(f[8], w5, accB[k]);
            accA[k] = fmaf(f[6], w6, accA[k]);
            accB[k] = fmaf(f[9], w6, accB[k]);
            accA[k] = fmaf(f[7], w7, accA[k]);
            accB[k] = fmaf(f[10], w7, accB[k]);
            accA[k] = fmaf(f[8], w8, accA[k]);
            accB[k] = fmaf(f[11], w8, accB[k]);
        }
        #pragma unroll
        for (int t = 0; t < 12; ++t) f[t] = g[t];
    }

    // ---- combine halves + softmax, pixel A then pixel B (reuse 18 KB buffer) ----
    #pragma unroll
    for (int k = 0; k < 9; ++k) part[half][k][p] = accA[k];
    __syncthreads();
    #pragma unroll
    for (int k = 0; k < 9; ++k) accA[k] = part[0][k][p] + part[1][k][p] + bias[k];
    __syncthreads();
    #pragma unroll
    for (int k = 0; k < 9; ++k) part[half][k][p] = accB[k];
    __syncthreads();
    #pragma unroll
    for (int k = 0; k < 9; ++k) accB[k] = part[0][k][p] + part[1][k][p] + bias[k];

    {
        float m = accA[0];
        #pragma unroll
        for (int k = 1; k < 9; ++k) m = fmaxf(m, accA[k]);
        float s = 0.f;
        #pragma unroll
        for (int k = 0; k < 9; ++k) { accA[k] = __expf(accA[k] - m); s += accA[k]; }
        const float inv = 1.f / s;
        #pragma unroll
        for (int k = 0; k < 9; ++k) accA[k] *= inv;
    }
    {
        float m = accB[0];
        #pragma unroll
        for (int k = 1; k < 9; ++k) m = fmaxf(m, accB[k]);
        float s = 0.f;
        #pragma unroll
        for (int k = 0; k < 9; ++k) { accB[k] = __expf(accB[k] - m); s += accB[k]; }
        const float inv = 1.f / s;
        #pragma unroll
        for (int k = 0; k < 9; ++k) accB[k] *= inv;
    }

    // ---- Phase 2: apply filters to this half's 32 channels, 2 pixels each ----
    const float* ib = inpt + (size_t)b * CC * HW + (size_t)half * 32 * HW;
    float* ob       = out  + (size_t)b * CC * HW + (size_t)half * 32 * HW;
    const int oA = rb + wx, oB = rc + wx;

    #pragma unroll
    for (int t = 0; t < 12; ++t) f[t] = ib[off[t]];          // prefetch c=0
    for (int c = 0; c < 32; ++c) {
        if (c < 31) {
            const float* in2 = ib + (size_t)(c + 1) * HW;
            #pragma unroll
            for (int t = 0; t < 12; ++t) g[t] = in2[off[t]];
        }
        float vA = accA[0] * f[0];
        float vB = accB[0] * f[3];
        vA = fmaf(accA[1], f[1],  vA);  vB = fmaf(accB[1], f[4],  vB);
        vA = fmaf(accA[2], f[2],  vA);  vB = fmaf(accB[2], f[5],  vB);
        vA = fmaf(accA[3], f[3],  vA);  vB = fmaf(accB[3], f[6],  vB);
        vA = fmaf(accA[4], f[4],  vA);  vB = fmaf(accB[4], f[7],  vB);
        vA = fmaf(accA[5], f[5],  vA);  vB = fmaf(accB[5], f[8],  vB);
        vA = fmaf(accA[6], f[6],  vA);  vB = fmaf(accB[6], f[9],  vB);
        vA = fmaf(accA[7], f[7],  vA);  vB = fmaf(accB[7], f[10], vB);
        vA = fmaf(accA[8], f[8],  vA);  vB = fmaf(accB[8], f[11], vB);
        ob[(size_t)c * HW + oA] = vA;
        ob[(size_t)c * HW + oB] = vB;
        #pragma unroll
        for (int t = 0; t < 12; ++t) f[t] = g[t];
    }
}

extern "C" void kernel_launch(void* const* d_in, const int* in_sizes, int n_in,
                              void* d_out, int out_size, void* d_ws, size_t ws_size,
                              hipStream_t stream) {
    const float* features = (const float*)d_in[0];
    const float* inpt     = (const float*)d_in[1];
    const float* wgt      = (const float*)d_in[2];
    const float* bias     = (const float*)d_in[3];
    float* out            = (float*)d_out;

    dim3 grid(WW / 64, HH / 8, BB);   // (4, 32, 4) = 512 blocks, 2/CU uniform
    dim3 block(512);
    pff_fused2c<<<grid, block, 0, stream>>>(features, inpt, wgt, bias, out);
}

// Round 6
// 74.336 us; speedup vs baseline: 1.3122x; 1.3122x over previous
//
#include <hip/hip_runtime.h>
#include <math.h>

// Problem constants (fixed by setup_inputs)
#define BB 4
#define NI 64
#define CC 64
#define HH 256
#define WW 256
#define HW (HH * WW)

// Tile geometry: 64w x 8h pixels per block, 512 threads =
// 2 channel-halves x 256 slots; each slot = 2 vertically adjacent pixels.
#define TW 64
#define TH 8
#define SR 10          // stencil rows = TH + 2
#define SC 66          // stencil cols = TW + 2
#define SE 660         // SR*SC stencil elements per channel
#define BUFW 672       // padded words per half-buffer
#define BUFSTRIDE 1344 // words per buffer (2 halves)

// numpy/jax "reflect" (mirror, edge not repeated), pad=1 so i in [-1, n]
__device__ __forceinline__ int refl(int i, int n) {
    i = (i < 0) ? -i : i;
    return (i >= n) ? (2 * n - 2 - i) : i;
}

// Lessons: R2 no reg cap (spill); R3 scalarize half (readfirstlane) so weights
// stay on s_load; R4/R5 latency-bound -> this round: LDS-stage the stencil tile
// (12 scattered VMEM/iter -> 3 coalesced VMEM + 12 conflict-free ds_read),
// double-buffered, loads issued one full iteration ahead of use.
__global__ __launch_bounds__(512) void pff_lds(
    const float* __restrict__ features,
    const float* __restrict__ inpt,
    const float* __restrict__ wgt,
    const float* __restrict__ bias,
    float* __restrict__ out)
{
    // 18 KB, time-shared: staging = 2 bufs x 2 halves x 672 words (2688 w),
    // then combine = part[2][9][256] (4608 w). Barrier-separated.
    __shared__ float lds[4608];

    const int tid  = threadIdx.x;
    const int half = __builtin_amdgcn_readfirstlane(tid >> 8);  // 0 or 1
    const int p    = tid & 255;
    const int c    = p & 63;      // col within tile
    const int tr   = p >> 6;      // thread-row 0..3 (2 pixel rows each)
    const int W0   = blockIdx.x * TW;
    const int H0   = blockIdx.y * TH;
    const int b    = blockIdx.z;

    // ---- channel-invariant staging offsets: 3 elements per thread ----
    // element e of the 10x66 tile; tile row 0 = global row H0-1, col 0 = W0-1
    int goff[3], loff[3];
    #pragma unroll
    for (int t = 0; t < 3; ++t) {
        int e = p + 256 * t;
        if (e >= SE) e -= 148;            // clamp tail into valid range
                                          // (duplicate writes carry identical values)
        loff[t] = e;
        const int row = e / SC;
        const int col = e - row * SC;
        const int gh = refl(H0 - 1 + row, HH);
        const int gw = refl(W0 - 1 + col, WW);
        goff[t] = gh * WW + gw;
    }

    float accA[9], accB[9];
    #pragma unroll
    for (int k = 0; k < 9; ++k) { accA[k] = 0.f; accB[k] = 0.f; }

    // ================= Phase 1: conv partials over 32 channels =================
    const float* fb = features + (size_t)b * NI * HW + (size_t)half * 32 * HW;
    float r0 = fb[goff[0]], r1 = fb[goff[1]], r2 = fb[goff[2]];   // ch 0

    for (int ni = 0; ni < 32; ++ni) {
        float* bw = &lds[(ni & 1) * BUFSTRIDE + half * BUFW];
        bw[loff[0]] = r0; bw[loff[1]] = r1; bw[loff[2]] = r2;
        if (ni < 31) {   // issue next channel's loads; consumed next iteration
            const float* fn = fb + (size_t)(ni + 1) * HW;
            r0 = fn[goff[0]]; r1 = fn[goff[1]]; r2 = fn[goff[2]];
        }
        __syncthreads();   // staged channel visible; prev-buf readers all done

        float f[12];
        #pragma unroll
        for (int rr = 0; rr < 4; ++rr) {
            const float* br = bw + (2 * tr + rr) * SC + c;
            f[rr * 3 + 0] = br[0];
            f[rr * 3 + 1] = br[1];
            f[rr * 3 + 2] = br[2];
        }

        const float* wn = wgt + (half * 32 + ni) * 9;   // scalar base -> s_load
        #pragma unroll
        for (int k = 0; k < 9; ++k) {
            const float* wk = wn + k * (NI * 9);        // wgt[9][NI][3][3]
            const float w0 = wk[0], w1 = wk[1], w2 = wk[2];
            const float w3 = wk[3], w4 = wk[4], w5 = wk[5];
            const float w6 = wk[6], w7 = wk[7], w8 = wk[8];
            // pixel A: tile rows 2tr..2tr+2 ; pixel B: rows 2tr+1..2tr+3
            accA[k] = fmaf(f[0],  w0, accA[k]);
            accB[k] = fmaf(f[3],  w0, accB[k]);
            accA[k] = fmaf(f[1],  w1, accA[k]);
            accB[k] = fmaf(f[4],  w1, accB[k]);
            accA[k] = fmaf(f[2],  w2, accA[k]);
            accB[k] = fmaf(f[5],  w2, accB[k]);
            accA[k] = fmaf(f[3],  w3, accA[k]);
            accB[k] = fmaf(f[6],  w3, accB[k]);
            accA[k] = fmaf(f[4],  w4, accA[k]);
            accB[k] = fmaf(f[7],  w4, accB[k]);
            accA[k] = fmaf(f[5],  w5, accA[k]);
            accB[k] = fmaf(f[8],  w5, accB[k]);
            accA[k] = fmaf(f[6],  w6, accA[k]);
            accB[k] = fmaf(f[9],  w6, accB[k]);
            accA[k] = fmaf(f[7],  w7, accA[k]);
            accB[k] = fmaf(f[10], w7, accB[k]);
            accA[k] = fmaf(f[8],  w8, accA[k]);
            accB[k] = fmaf(f[11], w8, accB[k]);
        }
    }

    // ================= combine halves + softmax (reuse LDS as part[]) ==========
    __syncthreads();   // staging reads done; repurpose lds
    #pragma unroll
    for (int k = 0; k < 9; ++k) lds[half * 2304 + k * 256 + p] = accA[k];
    __syncthreads();
    #pragma unroll
    for (int k = 0; k < 9; ++k)
        accA[k] = lds[k * 256 + p] + lds[2304 + k * 256 + p] + bias[k];
    __syncthreads();
    #pragma unroll
    for (int k = 0; k < 9; ++k) lds[half * 2304 + k * 256 + p] = accB[k];
    __syncthreads();
    #pragma unroll
    for (int k = 0; k < 9; ++k)
        accB[k] = lds[k * 256 + p] + lds[2304 + k * 256 + p] + bias[k];

    {
        float m = accA[0];
        #pragma unroll
        for (int k = 1; k < 9; ++k) m = fmaxf(m, accA[k]);
        float s = 0.f;
        #pragma unroll
        for (int k = 0; k < 9; ++k) { accA[k] = __expf(accA[k] - m); s += accA[k]; }
        const float inv = 1.f / s;
        #pragma unroll
        for (int k = 0; k < 9; ++k) accA[k] *= inv;
    }
    {
        float m = accB[0];
        #pragma unroll
        for (int k = 1; k < 9; ++k) m = fmaxf(m, accB[k]);
        float s = 0.f;
        #pragma unroll
        for (int k = 0; k < 9; ++k) { accB[k] = __expf(accB[k] - m); s += accB[k]; }
        const float inv = 1.f / s;
        #pragma unroll
        for (int k = 0; k < 9; ++k) accB[k] *= inv;
    }

    // ================= Phase 2: apply filters over 32 channels =================
    const float* ib = inpt + (size_t)b * CC * HW + (size_t)half * 32 * HW;
    float* ob       = out  + (size_t)b * CC * HW + (size_t)half * 32 * HW;
    const int oA = (H0 + 2 * tr) * WW + W0 + c;
    const int oB = oA + WW;

    r0 = ib[goff[0]]; r1 = ib[goff[1]]; r2 = ib[goff[2]];   // ch 0
    __syncthreads();   // part[] reads done; staging may overwrite

    for (int ch = 0; ch < 32; ++ch) {
        float* bw = &lds[(ch & 1) * BUFSTRIDE + half * BUFW];
        bw[loff[0]] = r0; bw[loff[1]] = r1; bw[loff[2]] = r2;
        if (ch < 31) {
            const float* in2 = ib + (size_t)(ch + 1) * HW;
            r0 = in2[goff[0]]; r1 = in2[goff[1]]; r2 = in2[goff[2]];
        }
        __syncthreads();

        float f[12];
        #pragma unroll
        for (int rr = 0; rr < 4; ++rr) {
            const float* br = bw + (2 * tr + rr) * SC + c;
            f[rr * 3 + 0] = br[0];
            f[rr * 3 + 1] = br[1];
            f[rr * 3 + 2] = br[2];
        }

        float vA = accA[0] * f[0];
        float vB = accB[0] * f[3];
        vA = fmaf(accA[1], f[1],  vA);  vB = fmaf(accB[1], f[4],  vB);
        vA = fmaf(accA[2], f[2],  vA);  vB = fmaf(accB[2], f[5],  vB);
        vA = fmaf(accA[3], f[3],  vA);  vB = fmaf(accB[3], f[6],  vB);
        vA = fmaf(accA[4], f[4],  vA);  vB = fmaf(accB[4], f[7],  vB);
        vA = fmaf(accA[5], f[5],  vA);  vB = fmaf(accB[5], f[8],  vB);
        vA = fmaf(accA[6], f[6],  vA);  vB = fmaf(accB[6], f[9],  vB);
        vA = fmaf(accA[7], f[7],  vA);  vB = fmaf(accB[7], f[10], vB);
        vA = fmaf(accA[8], f[8],  vA);  vB = fmaf(accB[8], f[11], vB);
        ob[(size_t)ch * HW + oA] = vA;
        ob[(size_t)ch * HW + oB] = vB;
    }
}

extern "C" void kernel_launch(void* const* d_in, const int* in_sizes, int n_in,
                              void* d_out, int out_size, void* d_ws, size_t ws_size,
                              hipStream_t stream) {
    const float* features = (const float*)d_in[0];
    const float* inpt     = (const float*)d_in[1];
    const float* wgt      = (const float*)d_in[2];
    const float* bias     = (const float*)d_in[3];
    float* out            = (float*)d_out;

    dim3 grid(WW / TW, HH / TH, BB);   // (4, 32, 4) = 512 blocks, 2/CU uniform
    dim3 block(512);
    pff_lds<<<grid, block, 0, stream>>>(features, inpt, wgt, bias, out);
}

// Round 7
// 70.304 us; speedup vs baseline: 1.3875x; 1.0573x over previous
//
#include <hip/hip_runtime.h>
#include <math.h>

// Problem constants (fixed by setup_inputs)
#define BB 4
#define NI 64
#define CC 64
#define HH 256
#define WW 256
#define HW (HH * WW)

// Block: 64w x 8h pixels, 512 threads = 2 channel-halves x 4 waves.
// Each wave: uniform (half, tr); 64 lanes x 2 vertically adjacent pixels.
// Wave stages its OWN 4-row x 66-col stencil strip -> no cross-wave sharing
// -> NO __syncthreads in the main loops (R6 lesson: the compiler drains
// vmcnt(0) at every barrier, killing the prefetch; per-wave LDS needs only
// in-order DS + lgkmcnt). Double-buffered; prefetch stays in flight.
#define SRW 68          // padded row stride (66 used)
#define BUFW 272        // 4 rows * 68
#define NBUF 2

// numpy/jax "reflect" (mirror, edge not repeated), pad=1 so i in [-1, n]
__device__ __forceinline__ int refl(int i, int n) {
    i = (i < 0) ? -i : i;
    return (i >= n) ? (2 * n - 2 - i) : i;
}

__global__ __launch_bounds__(512) void pff_wave(
    const float* __restrict__ features,
    const float* __restrict__ inpt,
    const float* __restrict__ wgt,
    const float* __restrict__ bias,
    float* __restrict__ out)
{
    __shared__ float stage[8][NBUF * BUFW];   // 17.4 KB, per-wave private
    __shared__ float part[2][9][256];         // 18 KB, combine only

    const int tid  = threadIdx.x;
    const int wv   = __builtin_amdgcn_readfirstlane(tid >> 6);  // 0..7 scalar
    const int half = wv >> 2;                 // scalar
    const int tr   = wv & 3;                  // scalar thread-row
    const int l    = tid & 63;
    const int p    = tid & 255;
    const int W0 = blockIdx.x * 64;
    const int H0 = blockIdx.y * 8;
    const int b  = blockIdx.z;

    // per-wave stencil strip: global rows H0+2tr-1 .. H0+2tr+2, cols W0-1..W0+64
    // element e in [0,264): row=e/66, col=e%66. 4 loads/lane + 1 for lanes 0-7.
    int goff[5], loff[5];
    #pragma unroll
    for (int t = 0; t < 5; ++t) {
        const int e = (t < 4) ? (l + 64 * t) : (256 + (l & 7));
        const int row = e / 66, col = e - row * 66;
        loff[t] = row * SRW + col;
        goff[t] = refl(H0 + 2 * tr - 1 + row, HH) * WW + refl(W0 - 1 + col, WW);
    }
    const bool do5 = (l < 8);

    float accA[9], accB[9];
    #pragma unroll
    for (int k = 0; k < 9; ++k) { accA[k] = 0.f; accB[k] = 0.f; }

    float* sb = &stage[wv][0];

    // ================= Phase 1: conv partials over this half's 32 channels =====
    const float* fb = features + (size_t)b * NI * HW + (size_t)half * 32 * HW;
    float r0 = fb[goff[0]], r1 = fb[goff[1]], r2 = fb[goff[2]], r3 = fb[goff[3]];
    float r4 = do5 ? fb[goff[4]] : 0.f;

    for (int ni = 0; ni < 32; ++ni) {
        float* bw = sb + (ni & 1) * BUFW;
        bw[loff[0]] = r0; bw[loff[1]] = r1; bw[loff[2]] = r2; bw[loff[3]] = r3;
        if (do5) bw[loff[4]] = r4;
        if (ni < 31) {   // prefetch next channel; NO barrier -> stays in flight
            const float* fn = fb + (size_t)(ni + 1) * HW;
            r0 = fn[goff[0]]; r1 = fn[goff[1]]; r2 = fn[goff[2]]; r3 = fn[goff[3]];
            if (do5) r4 = fn[goff[4]];
        }

        float f[12];
        #pragma unroll
        for (int rr = 0; rr < 4; ++rr) {     // same-wave DS: ordered, lgkm only
            const float* br = bw + rr * SRW + l;
            f[rr * 3 + 0] = br[0];
            f[rr * 3 + 1] = br[1];
            f[rr * 3 + 2] = br[2];
        }

        const float* wn = wgt + (half * 32 + ni) * 9;   // scalar base -> s_load
        #pragma unroll
        for (int k = 0; k < 9; ++k) {
            const float* wk = wn + k * (NI * 9);        // wgt[9][NI][3][3]
            const float w0 = wk[0], w1 = wk[1], w2 = wk[2];
            const float w3 = wk[3], w4 = wk[4], w5 = wk[5];
            const float w6 = wk[6], w7 = wk[7], w8 = wk[8];
            // pixel A: strip rows 0,1,2 ; pixel B: strip rows 1,2,3
            accA[k] = fmaf(f[0],  w0, accA[k]);
            accB[k] = fmaf(f[3],  w0, accB[k]);
            accA[k] = fmaf(f[1],  w1, accA[k]);
            accB[k] = fmaf(f[4],  w1, accB[k]);
            accA[k] = fmaf(f[2],  w2, accA[k]);
            accB[k] = fmaf(f[5],  w2, accB[k]);
            accA[k] = fmaf(f[3],  w3, accA[k]);
            accB[k] = fmaf(f[6],  w3, accB[k]);
            accA[k] = fmaf(f[4],  w4, accA[k]);
            accB[k] = fmaf(f[7],  w4, accB[k]);
            accA[k] = fmaf(f[5],  w5, accA[k]);
            accB[k] = fmaf(f[8],  w5, accB[k]);
            accA[k] = fmaf(f[6],  w6, accA[k]);
            accB[k] = fmaf(f[9],  w6, accB[k]);
            accA[k] = fmaf(f[7],  w7, accA[k]);
            accB[k] = fmaf(f[10], w7, accB[k]);
            accA[k] = fmaf(f[8],  w8, accA[k]);
            accB[k] = fmaf(f[11], w8, accB[k]);
        }
    }

    // prefetch phase-2 channel 0 now; latency hides under combine/softmax
    const float* ib = inpt + (size_t)b * CC * HW + (size_t)half * 32 * HW;
    r0 = ib[goff[0]]; r1 = ib[goff[1]]; r2 = ib[goff[2]]; r3 = ib[goff[3]];
    if (do5) r4 = ib[goff[4]];

    // ================= combine halves + softmax (one-time barriers) ===========
    #pragma unroll
    for (int k = 0; k < 9; ++k) part[half][k][p] = accA[k];
    __syncthreads();
    #pragma unroll
    for (int k = 0; k < 9; ++k) accA[k] = part[0][k][p] + part[1][k][p] + bias[k];
    __syncthreads();
    #pragma unroll
    for (int k = 0; k < 9; ++k) part[half][k][p] = accB[k];
    __syncthreads();
    #pragma unroll
    for (int k = 0; k < 9; ++k) accB[k] = part[0][k][p] + part[1][k][p] + bias[k];

    {
        float m = accA[0];
        #pragma unroll
        for (int k = 1; k < 9; ++k) m = fmaxf(m, accA[k]);
        float s = 0.f;
        #pragma unroll
        for (int k = 0; k < 9; ++k) { accA[k] = __expf(accA[k] - m); s += accA[k]; }
        const float inv = 1.f / s;
        #pragma unroll
        for (int k = 0; k < 9; ++k) accA[k] *= inv;
    }
    {
        float m = accB[0];
        #pragma unroll
        for (int k = 1; k < 9; ++k) m = fmaxf(m, accB[k]);
        float s = 0.f;
        #pragma unroll
        for (int k = 0; k < 9; ++k) { accB[k] = __expf(accB[k] - m); s += accB[k]; }
        const float inv = 1.f / s;
        #pragma unroll
        for (int k = 0; k < 9; ++k) accB[k] *= inv;
    }

    // ================= Phase 2: apply filters over 32 channels (barrier-free) ==
    float* ob = out + (size_t)b * CC * HW + (size_t)half * 32 * HW;
    const int oA = (H0 + 2 * tr) * WW + W0 + l;
    const int oB = oA + WW;

    for (int ch = 0; ch < 32; ++ch) {
        float* bw = sb + (ch & 1) * BUFW;    // own-wave buffer: no hazard
        bw[loff[0]] = r0; bw[loff[1]] = r1; bw[loff[2]] = r2; bw[loff[3]] = r3;
        if (do5) bw[loff[4]] = r4;
        if (ch < 31) {
            const float* in2 = ib + (size_t)(ch + 1) * HW;
            r0 = in2[goff[0]]; r1 = in2[goff[1]]; r2 = in2[goff[2]]; r3 = in2[goff[3]];
            if (do5) r4 = in2[goff[4]];
        }

        float f[12];
        #pragma unroll
        for (int rr = 0; rr < 4; ++rr) {
            const float* br = bw + rr * SRW + l;
            f[rr * 3 + 0] = br[0];
            f[rr * 3 + 1] = br[1];
            f[rr * 3 + 2] = br[2];
        }

        float vA = accA[0] * f[0];
        float vB = accB[0] * f[3];
        vA = fmaf(accA[1], f[1],  vA);  vB = fmaf(accB[1], f[4],  vB);
        vA = fmaf(accA[2], f[2],  vA);  vB = fmaf(accB[2], f[5],  vB);
        vA = fmaf(accA[3], f[3],  vA);  vB = fmaf(accB[3], f[6],  vB);
        vA = fmaf(accA[4], f[4],  vA);  vB = fmaf(accB[4], f[7],  vB);
        vA = fmaf(accA[5], f[5],  vA);  vB = fmaf(accB[5], f[8],  vB);
        vA = fmaf(accA[6], f[6],  vA);  vB = fmaf(accB[6], f[9],  vB);
        vA = fmaf(accA[7], f[7],  vA);  vB = fmaf(accB[7], f[10], vB);
        vA = fmaf(accA[8], f[8],  vA);  vB = fmaf(accB[8], f[11], vB);
        ob[(size_t)ch * HW + oA] = vA;
        ob[(size_t)ch * HW + oB] = vB;
    }
}

extern "C" void kernel_launch(void* const* d_in, const int* in_sizes, int n_in,
                              void* d_out, int out_size, void* d_ws, size_t ws_size,
                              hipStream_t stream) {
    const float* features = (const float*)d_in[0];
    const float* inpt     = (const float*)d_in[1];
    const float* wgt      = (const float*)d_in[2];
    const float* bias     = (const float*)d_in[3];
    float* out            = (float*)d_out;

    dim3 grid(WW / 64, HH / 8, BB);   // (4, 32, 4) = 512 blocks, 2/CU uniform
    dim3 block(512);
    pff_wave<<<grid, block, 0, stream>>>(features, inpt, wgt, bias, out);
}